// Round 9
// baseline (162.904 us; speedup 1.0000x reference)
//
#include <hip/hip_runtime.h>
#include <hip/hip_bf16.h>

// PAM module: B=4, N=4096 (64x64), C=64.
// out[b,n,c] = gamma * sum_m softmax_row(q@k^T)[m,n] * v[m,c] + x[b,n,c]
//
// bf16 MFMA; energy recomputed. log2e folded into Wq/bq; softmax normalizer
// folded into QK MFMA C-init (lr = -log2(rowsum)); P built in registers
// (K=16 PV MFMA identity), truncation bf16 pack.
// KEY: q/k/v^T stored in MFMA-FRAGMENT-MAJOR layout (per 16-tile:
// [half][lane][8elems]) so k2/k3 stream operands with fully-coalesced
// per-wave frag loads straight from global -> NO LDS, NO BARRIERS in the
// hot kernels; L1 dedups the 4x cross-wave reuse, L2 backstops.
//  k0z: W -> W^T bf16 (Wq scaled by log2e), zero s-buffer
//  k1 : projections (grid 768); outputs written frag-major via LDS staging
//  k2 : partial rowsums, n-split 4, no-LDS streaming (grid 1024)
//  r2 : lr = -log2(s) ; out <- x
//  k3 : out += gamma * exp2(e'+lr) @ v, m-split 4, no-LDS streaming (grid 1024)

typedef __attribute__((ext_vector_type(8))) short short8;
typedef __attribute__((ext_vector_type(4))) short short4b;
typedef __attribute__((ext_vector_type(4))) float f32x4;
typedef __attribute__((ext_vector_type(4))) unsigned int u32x4;
typedef __attribute__((ext_vector_type(2))) unsigned int u32x2;

#define DEV static __device__ __forceinline__
#define LOG2E 1.4426950408889634f

DEV unsigned short f2bf(float f) {
    __hip_bfloat16 h = __float2bfloat16(f);
    return __builtin_bit_cast(unsigned short, h);
}
DEV unsigned int pack2(float lo, float hi) {
    return (unsigned int)f2bf(lo) | ((unsigned int)f2bf(hi) << 16);
}
DEV unsigned int pack2t(float lo, float hi) {   // truncation-pack (P>=0, no NaN)
    unsigned int ul = __builtin_bit_cast(unsigned int, lo);
    unsigned int uh = __builtin_bit_cast(unsigned int, hi);
    return (uh & 0xffff0000u) | (ul >> 16);
}
DEV f32x4 MFMA32(short8 a, short8 b, f32x4 c) {
    return __builtin_amdgcn_mfma_f32_16x16x32_bf16(a, b, c, 0, 0, 0);
}
DEV f32x4 MFMA16(short4b a, short4b b, f32x4 c) {
#if __has_builtin(__builtin_amdgcn_mfma_f32_16x16x16_bf16)
    return __builtin_amdgcn_mfma_f32_16x16x16_bf16(a, b, c, 0, 0, 0);
#else
    return __builtin_amdgcn_mfma_f32_16x16x16bf16_1k(a, b, c, 0, 0, 0);
#endif
}
DEV float EXP2(float x) {
#if __has_builtin(__builtin_amdgcn_exp2f)
    return __builtin_amdgcn_exp2f(x);
#else
    return exp2f(x);
#endif
}

// Fragment-major layouts (shorts), gmt/gnt = global 16-tile index in [0,1024):
//  qf/kf: [gmt][h(2)][lane(64)][e(8)]  -> 1024 shorts (2KB) per tile
//         element = q[tile*16 + (lane&15)][h*32 + 8*(lane>>4) + e]
//  vf   : [gmt][ct(4)][lane(64)][e(4)] -> 1024 shorts (2KB) per tile
//         element = v[tile*16 + 4*(lane>>4) + e][ct*16 + (lane&15)]
// ws layout (bytes)
#define OFF_Q    0u          // qf 2 MB
#define OFF_K    2097152u    // kf 2 MB
#define OFF_VT   4194304u    // vf 2 MB
#define OFF_WT   6291456u    // [3][64][64] bf16 = 24 KB
#define OFF_S    6316032u    // [16384] f32 = 64 KB (row sums, atomic)
#define OFF_LR   6381568u    // [16384] f32 = 64 KB (lr = -log2 s)

// ---------------- k0z: weight transpose (+log2e on Wq) + zero s ----------------
__global__ __launch_bounds__(256) void k0z(const float* __restrict__ Wq,
                                           const float* __restrict__ Wk,
                                           const float* __restrict__ Wv,
                                           unsigned short* __restrict__ wt,
                                           float* __restrict__ sbuf) {
    int e = blockIdx.x * 256 + threadIdx.x;   // grid 64 -> [0,16384)
    sbuf[e] = 0.0f;
    if (e < 3 * 4096) {
        int w3 = e >> 12, rem = e & 4095, f = rem >> 6, c = rem & 63;
        const float* W = (w3 == 0) ? Wq : (w3 == 1) ? Wk : Wv;
        float s = (w3 == 0) ? LOG2E : 1.0f;
        wt[e] = f2bf(W[c * 64 + f] * s);   // wt[w3][f][c] = W[c][f] * s
    }
}

// ---------------- k1: projections -> frag-major outputs (grid 768) ----------------
__global__ __launch_bounds__(256) void k1_proj(const float* __restrict__ x,
                                               const unsigned short* __restrict__ wt,
                                               const float* __restrict__ bq,
                                               const float* __restrict__ bk,
                                               const float* __restrict__ bv,
                                               unsigned short* __restrict__ qf,
                                               unsigned short* __restrict__ kf,
                                               unsigned short* __restrict__ vf) {
    __shared__ __align__(16) char XT[8192];     // [64 m][128B c] swz
    __shared__ __align__(16) char WT1[8192];    // [64 f][128B c] swz
    __shared__ __align__(16) char OT[9216];     // [64][72 shorts] staging
    int t = threadIdx.x, blk = blockIdx.x;
    int w3 = blk >> 8, rb = blk & 255;

    {   // stage x tile (fp32 -> bf16, swizzled)
        int m = t >> 2, q4 = t & 3;
        const f32x4* xs = (const f32x4*)(x + (size_t)(rb * 64 + m) * 64 + q4 * 16);
        f32x4 fa = xs[0], f2 = xs[1], fc = xs[2], fd = xs[3];
        u32x4 u0 = { pack2(fa[0],fa[1]), pack2(fa[2],fa[3]), pack2(f2[0],f2[1]), pack2(f2[2],f2[3]) };
        u32x4 u1 = { pack2(fc[0],fc[1]), pack2(fc[2],fc[3]), pack2(fd[0],fd[1]), pack2(fd[2],fd[3]) };
        int sw = (m & 7) << 4;
        *(u32x4*)(XT + m * 128 + ((q4 * 32) ^ sw)) = u0;
        *(u32x4*)(XT + m * 128 + ((q4 * 32 + 16) ^ sw)) = u1;
    }
    {   // stage this projection's W^T
        int f = t >> 2, q4 = t & 3;
        const u32x4* s = (const u32x4*)(wt + w3 * 4096 + f * 64 + q4 * 16);
        u32x4 u0 = s[0], u1 = s[1];
        int sw = (f & 7) << 4;
        *(u32x4*)(WT1 + f * 128 + ((q4 * 32) ^ sw)) = u0;
        *(u32x4*)(WT1 + f * 128 + ((q4 * 32 + 16) ^ sw)) = u1;
    }
    __syncthreads();

    int lane = t & 63, wid = t >> 6, g = lane >> 4, ln = lane & 15;
    int arow = wid * 16 + ln;
    short8 a0 = *(const short8*)(XT + arow * 128 + ((16 * g) ^ ((arow & 7) << 4)));
    short8 a1 = *(const short8*)(XT + arow * 128 + ((64 + 16 * g) ^ ((arow & 7) << 4)));
    const float* bias = (w3 == 0) ? bq : (w3 == 1) ? bk : bv;
    float bscale = (w3 == 0) ? LOG2E : 1.0f;

    unsigned short* ot = (unsigned short*)OT;
    #pragma unroll
    for (int fb = 0; fb < 4; ++fb) {
        int frow = fb * 16 + ln;
        short8 b0 = *(const short8*)(WT1 + frow * 128 + ((16 * g) ^ ((frow & 7) << 4)));
        short8 b1 = *(const short8*)(WT1 + frow * 128 + ((64 + 16 * g) ^ ((frow & 7) << 4)));
        f32x4 acc = {0.f, 0.f, 0.f, 0.f};
        acc = MFMA32(a0, b0, acc);
        acc = MFMA32(a1, b1, acc);
        float bval = bias[frow] * bscale;
        int mloc = wid * 16 + 4 * g;
        if (w3 < 2) {   // q,k: OT[m][c]
            #pragma unroll
            for (int r = 0; r < 4; ++r)
                ot[(mloc + r) * 72 + frow] = f2bf(acc[r] + bval);
        } else {        // v: OT[c][m]
            #pragma unroll
            for (int r = 0; r < 4; ++r)
                ot[frow * 72 + mloc + r] = f2bf(acc[r] + bval);
        }
    }
    __syncthreads();

    // frag-major coalesced global writes
    int mt_l = t >> 6, l = t & 63;
    size_t gmt = (size_t)rb * 4 + mt_l;
    if (w3 < 2) {
        unsigned short* dst = ((w3 == 0) ? qf : kf) + gmt * 1024;
        #pragma unroll
        for (int h = 0; h < 2; ++h) {
            u32x4 val = *(const u32x4*)(ot + (mt_l * 16 + (l & 15)) * 72 + h * 32 + 8 * (l >> 4));
            *(u32x4*)(dst + h * 512 + l * 8) = val;
        }
    } else {
        unsigned short* dst = vf + gmt * 1024;
        #pragma unroll
        for (int ct = 0; ct < 4; ++ct) {
            u32x2 val = *(const u32x2*)(ot + (ct * 16 + (l & 15)) * 72 + mt_l * 16 + 4 * (l >> 4));
            *(u32x2*)(dst + ct * 256 + l * 4) = val;
        }
    }
}

// ---------------- k2: partial row sums, no-LDS streaming ----------------
// grid 1024: blk = b*256 + ns*64 + mb. Wave owns m-tile (pinned A-frags),
// streams 64 coalesced kf frag-tiles of its n-quarter. No barriers.
__global__ __launch_bounds__(256, 4) void k2_rowsum(const unsigned short* __restrict__ qf,
                                                    const unsigned short* __restrict__ kf,
                                                    float* __restrict__ sbuf) {
    int t = threadIdx.x, blk = blockIdx.x;
    int b = blk >> 8, ns = (blk >> 6) & 3, mb = blk & 63;
    int lane = t & 63, wid = t >> 6, g = lane >> 4, ln = lane & 15;

    size_t mt_g = (size_t)b * 256 + mb * 4 + wid;
    short8 a0 = *(const short8*)(qf + mt_g * 1024 + lane * 8);
    short8 a1 = *(const short8*)(qf + mt_g * 1024 + 512 + lane * 8);

    const unsigned short* kfb = kf + ((size_t)b * 256 + ns * 64) * 1024 + lane * 8;
    short8 kb0 = *(const short8*)(kfb);
    short8 kb1 = *(const short8*)(kfb + 512);

    f32x4 z = {0.f, 0.f, 0.f, 0.f};
    float acc0 = 0.f, acc1 = 0.f, acc2 = 0.f, acc3 = 0.f;
    for (int nt = 0; nt < 64; ++nt) {
        short8 nb0, nb1;
        if (nt < 63) {
            const unsigned short* kp = kfb + (size_t)(nt + 1) * 1024;
            nb0 = *(const short8*)(kp);
            nb1 = *(const short8*)(kp + 512);
        }
        f32x4 e = MFMA32(a1, kb1, MFMA32(a0, kb0, z));
        acc0 += EXP2(e[0]); acc1 += EXP2(e[1]);
        acc2 += EXP2(e[2]); acc3 += EXP2(e[3]);
        kb0 = nb0; kb1 = nb1;
    }
    #pragma unroll
    for (int msk = 1; msk < 16; msk <<= 1) {
        acc0 += __shfl_xor(acc0, msk);
        acc1 += __shfl_xor(acc1, msk);
        acc2 += __shfl_xor(acc2, msk);
        acc3 += __shfl_xor(acc3, msk);
    }
    if (ln == 0) {
        float* base = sbuf + b * 4096 + (mb * 4 + wid) * 16 + 4 * g;
        unsafeAtomicAdd(base + 0, acc0);
        unsafeAtomicAdd(base + 1, acc1);
        unsafeAtomicAdd(base + 2, acc2);
        unsafeAtomicAdd(base + 3, acc3);
    }
}

// ---------------- r2: lr = -log2(s) ; out <- x ----------------
__global__ __launch_bounds__(256) void r2_init(const float* __restrict__ sbuf,
                                               float* __restrict__ lrbuf,
                                               const float* __restrict__ x,
                                               float* __restrict__ outp) {
    int tid = blockIdx.x * 256 + threadIdx.x;   // grid 1024
    if (tid < 16384) lrbuf[tid] = -__log2f(sbuf[tid]);
    f32x4 v = *(const f32x4*)(x + 4 * (size_t)tid);
    *(f32x4*)(outp + 4 * (size_t)tid) = v;
}

// ---------------- k3: out += gamma * exp2(e'+lr) @ v, no-LDS streaming ----------------
// grid 1024: blk = b*256 + ms*64 + nblk. Wave owns n-tile (pinned kf frags),
// streams 64 m-tiles: qf A-frags + vf B-frags + lr, all coalesced. No barriers.
__global__ __launch_bounds__(256, 4) void k3_out(const unsigned short* __restrict__ qf,
                                                 const unsigned short* __restrict__ kf,
                                                 const unsigned short* __restrict__ vf,
                                                 const float* __restrict__ lrbuf,
                                                 const float* __restrict__ gamma,
                                                 float* __restrict__ outp) {
    int t = threadIdx.x, blk = blockIdx.x;
    int b = blk >> 8, ms = (blk >> 6) & 3, nblk = blk & 63;
    int lane = t & 63, wid = t >> 6, g = lane >> 4, ln = lane & 15;

    size_t nt_g = (size_t)b * 256 + nblk * 4 + wid;
    short8 kb0 = *(const short8*)(kf + nt_g * 1024 + lane * 8);
    short8 kb1 = *(const short8*)(kf + nt_g * 1024 + 512 + lane * 8);

    size_t mtbase = (size_t)b * 256 + ms * 64;
    const unsigned short* qb = qf + mtbase * 1024 + lane * 8;
    const unsigned short* vb = vf + mtbase * 1024 + lane * 4;
    const float* lrb = lrbuf + b * 4096 + ms * 1024 + 4 * g;

    // chunk 0
    short8 as0 = *(const short8*)(qb);
    short8 as1 = *(const short8*)(qb + 512);
    short4b vv0 = *(const short4b*)(vb);
    short4b vv1 = *(const short4b*)(vb + 256);
    short4b vv2 = *(const short4b*)(vb + 512);
    short4b vv3 = *(const short4b*)(vb + 768);
    f32x4 lc = *(const f32x4*)(lrb);

    f32x4 z = {0.f, 0.f, 0.f, 0.f};
    f32x4 oacc[4] = {z, z, z, z};

    for (int mt = 0; mt < 64; ++mt) {
        short8 nas0, nas1;
        short4b nv0, nv1, nv2, nv3;
        f32x4 lnx;
        if (mt < 63) {   // coalesced register prefetch of tile mt+1
            const unsigned short* qp = qb + (size_t)(mt + 1) * 1024;
            nas0 = *(const short8*)(qp);
            nas1 = *(const short8*)(qp + 512);
            const unsigned short* vp = vb + (size_t)(mt + 1) * 1024;
            nv0 = *(const short4b*)(vp);
            nv1 = *(const short4b*)(vp + 256);
            nv2 = *(const short4b*)(vp + 512);
            nv3 = *(const short4b*)(vp + 768);
            lnx = *(const f32x4*)(lrb + (mt + 1) * 16);
        }
        // QK^T, C-init = lr -> p = exp2(e)
        f32x4 e = MFMA32(as1, kb1, MFMA32(as0, kb0, lc));
        float p0 = EXP2(e[0]), p1 = EXP2(e[1]), p2 = EXP2(e[2]), p3 = EXP2(e[3]);
        u32x2 pw = { pack2t(p0, p1), pack2t(p2, p3) };
        short4b pa = __builtin_bit_cast(short4b, pw);
        oacc[0] = MFMA16(pa, vv0, oacc[0]);
        oacc[1] = MFMA16(pa, vv1, oacc[1]);
        oacc[2] = MFMA16(pa, vv2, oacc[2]);
        oacc[3] = MFMA16(pa, vv3, oacc[3]);
        as0 = nas0; as1 = nas1;
        vv0 = nv0; vv1 = nv1; vv2 = nv2; vv3 = nv3;
        lc = lnx;
    }

    float gm = gamma[0];
    int nr = b * 4096 + (nblk * 4 + wid) * 16 + 4 * g;
    #pragma unroll
    for (int ct = 0; ct < 4; ++ct) {
        #pragma unroll
        for (int r = 0; r < 4; ++r)
            unsafeAtomicAdd(outp + (size_t)(nr + r) * 64 + ct * 16 + ln, gm * oacc[ct][r]);
    }
}

extern "C" void kernel_launch(void* const* d_in, const int* in_sizes, int n_in,
                              void* d_out, int out_size, void* d_ws, size_t ws_size,
                              hipStream_t stream) {
    const float* x  = (const float*)d_in[0];
    const float* Wq = (const float*)d_in[1];
    const float* bq = (const float*)d_in[2];
    const float* Wk = (const float*)d_in[3];
    const float* bk = (const float*)d_in[4];
    const float* Wv = (const float*)d_in[5];
    const float* bv = (const float*)d_in[6];
    const float* gm = (const float*)d_in[7];
    char* ws = (char*)d_ws;
    float* outp = (float*)d_out;

    unsigned short* qf = (unsigned short*)(ws + OFF_Q);
    unsigned short* kf = (unsigned short*)(ws + OFF_K);
    unsigned short* vf = (unsigned short*)(ws + OFF_VT);
    unsigned short* wt = (unsigned short*)(ws + OFF_WT);
    float* sbuf        = (float*)(ws + OFF_S);
    float* lrbuf       = (float*)(ws + OFF_LR);

    k0z<<<64, 256, 0, stream>>>(Wq, Wk, Wv, wt, sbuf);
    k1_proj<<<768, 256, 0, stream>>>(x, wt, bq, bk, bv, qf, kf, vf);
    k2_rowsum<<<1024, 256, 0, stream>>>(qf, kf, sbuf);
    r2_init<<<1024, 256, 0, stream>>>(sbuf, lrbuf, x, outp);
    k3_out<<<1024, 256, 0, stream>>>(qf, kf, vf, lrbuf, gm, outp);
}

// Round 10
// 156.201 us; speedup vs baseline: 1.0429x; 1.0429x over previous
//
#include <hip/hip_runtime.h>
#include <hip/hip_bf16.h>

// PAM module: B=4, N=4096 (64x64), C=64.
// out[b,n,c] = gamma * sum_m softmax_row(q@k^T)[m,n] * v[m,c] + x[b,n,c]
//
// bf16 MFMA; energy recomputed. log2e folded into Wq/bq; softmax normalizer
// folded into QK MFMA C-init (lr = -log2(rowsum)); P built in registers
// (K=16 PV MFMA identity), truncation bf16 pack.
// q/k/v^T stored MFMA-FRAGMENT-MAJOR so k2/k3 stream operands with
// fully-coalesced per-wave frag loads straight from global (no LDS/barriers).
// R10: hot loops UNROLL-2 with 2-tile-ahead register prefetch -> two
// independent MFMA chains per iteration + 2x loads in flight (covers L2
// latency that stalled R9's depth-1 pipeline).
//  k0z: W -> W^T bf16 (Wq scaled by log2e), zero s-buffer
//  k1 : projections (grid 768); outputs written frag-major via LDS staging
//  k2 : partial rowsums, n-split 4, no-LDS streaming, unroll-2 (grid 1024)
//  r2 : lr = -log2(s) ; out <- x
//  k3 : out += gamma * exp2(e'+lr) @ v, m-split 4, no-LDS, unroll-2 (grid 1024)

typedef __attribute__((ext_vector_type(8))) short short8;
typedef __attribute__((ext_vector_type(4))) short short4b;
typedef __attribute__((ext_vector_type(4))) float f32x4;
typedef __attribute__((ext_vector_type(4))) unsigned int u32x4;
typedef __attribute__((ext_vector_type(2))) unsigned int u32x2;

#define DEV static __device__ __forceinline__
#define LOG2E 1.4426950408889634f

DEV unsigned short f2bf(float f) {
    __hip_bfloat16 h = __float2bfloat16(f);
    return __builtin_bit_cast(unsigned short, h);
}
DEV unsigned int pack2(float lo, float hi) {
    return (unsigned int)f2bf(lo) | ((unsigned int)f2bf(hi) << 16);
}
DEV unsigned int pack2t(float lo, float hi) {   // truncation-pack (P>=0, no NaN)
    unsigned int ul = __builtin_bit_cast(unsigned int, lo);
    unsigned int uh = __builtin_bit_cast(unsigned int, hi);
    return (uh & 0xffff0000u) | (ul >> 16);
}
DEV f32x4 MFMA32(short8 a, short8 b, f32x4 c) {
    return __builtin_amdgcn_mfma_f32_16x16x32_bf16(a, b, c, 0, 0, 0);
}
DEV f32x4 MFMA16(short4b a, short4b b, f32x4 c) {
#if __has_builtin(__builtin_amdgcn_mfma_f32_16x16x16_bf16)
    return __builtin_amdgcn_mfma_f32_16x16x16_bf16(a, b, c, 0, 0, 0);
#else
    return __builtin_amdgcn_mfma_f32_16x16x16bf16_1k(a, b, c, 0, 0, 0);
#endif
}
DEV float EXP2(float x) {
#if __has_builtin(__builtin_amdgcn_exp2f)
    return __builtin_amdgcn_exp2f(x);
#else
    return exp2f(x);
#endif
}

// Fragment-major layouts (shorts), tile = global 16-row tile index [0,1024):
//  qf/kf: [tile][h(2)][lane(64)][e(8)] ; element = q[tile*16+(l&15)][h*32+8*(l>>4)+e]
//  vf   : [tile][ct(4)][lane(64)][e(4)]; element = v[tile*16+4*(l>>4)+e][ct*16+(l&15)]
// ws layout (bytes)
#define OFF_Q    0u
#define OFF_K    2097152u
#define OFF_VT   4194304u
#define OFF_WT   6291456u
#define OFF_S    6316032u
#define OFF_LR   6381568u

// ---------------- k0z: weight transpose (+log2e on Wq) + zero s ----------------
__global__ __launch_bounds__(256) void k0z(const float* __restrict__ Wq,
                                           const float* __restrict__ Wk,
                                           const float* __restrict__ Wv,
                                           unsigned short* __restrict__ wt,
                                           float* __restrict__ sbuf) {
    int e = blockIdx.x * 256 + threadIdx.x;   // grid 64 -> [0,16384)
    sbuf[e] = 0.0f;
    if (e < 3 * 4096) {
        int w3 = e >> 12, rem = e & 4095, f = rem >> 6, c = rem & 63;
        const float* W = (w3 == 0) ? Wq : (w3 == 1) ? Wk : Wv;
        float s = (w3 == 0) ? LOG2E : 1.0f;
        wt[e] = f2bf(W[c * 64 + f] * s);   // wt[w3][f][c] = W[c][f] * s
    }
}

// ---------------- k1: projections -> frag-major outputs (grid 768) ----------------
__global__ __launch_bounds__(256) void k1_proj(const float* __restrict__ x,
                                               const unsigned short* __restrict__ wt,
                                               const float* __restrict__ bq,
                                               const float* __restrict__ bk,
                                               const float* __restrict__ bv,
                                               unsigned short* __restrict__ qf,
                                               unsigned short* __restrict__ kf,
                                               unsigned short* __restrict__ vf) {
    __shared__ __align__(16) char XT[8192];
    __shared__ __align__(16) char WT1[8192];
    __shared__ __align__(16) char OT[9216];
    int t = threadIdx.x, blk = blockIdx.x;
    int w3 = blk >> 8, rb = blk & 255;

    {   // stage x tile (fp32 -> bf16, swizzled)
        int m = t >> 2, q4 = t & 3;
        const f32x4* xs = (const f32x4*)(x + (size_t)(rb * 64 + m) * 64 + q4 * 16);
        f32x4 fa = xs[0], f2 = xs[1], fc = xs[2], fd = xs[3];
        u32x4 u0 = { pack2(fa[0],fa[1]), pack2(fa[2],fa[3]), pack2(f2[0],f2[1]), pack2(f2[2],f2[3]) };
        u32x4 u1 = { pack2(fc[0],fc[1]), pack2(fc[2],fc[3]), pack2(fd[0],fd[1]), pack2(fd[2],fd[3]) };
        int sw = (m & 7) << 4;
        *(u32x4*)(XT + m * 128 + ((q4 * 32) ^ sw)) = u0;
        *(u32x4*)(XT + m * 128 + ((q4 * 32 + 16) ^ sw)) = u1;
    }
    {   // stage this projection's W^T
        int f = t >> 2, q4 = t & 3;
        const u32x4* s = (const u32x4*)(wt + w3 * 4096 + f * 64 + q4 * 16);
        u32x4 u0 = s[0], u1 = s[1];
        int sw = (f & 7) << 4;
        *(u32x4*)(WT1 + f * 128 + ((q4 * 32) ^ sw)) = u0;
        *(u32x4*)(WT1 + f * 128 + ((q4 * 32 + 16) ^ sw)) = u1;
    }
    __syncthreads();

    int lane = t & 63, wid = t >> 6, g = lane >> 4, ln = lane & 15;
    int arow = wid * 16 + ln;
    short8 a0 = *(const short8*)(XT + arow * 128 + ((16 * g) ^ ((arow & 7) << 4)));
    short8 a1 = *(const short8*)(XT + arow * 128 + ((64 + 16 * g) ^ ((arow & 7) << 4)));
    const float* bias = (w3 == 0) ? bq : (w3 == 1) ? bk : bv;
    float bscale = (w3 == 0) ? LOG2E : 1.0f;

    unsigned short* ot = (unsigned short*)OT;
    #pragma unroll
    for (int fb = 0; fb < 4; ++fb) {
        int frow = fb * 16 + ln;
        short8 b0 = *(const short8*)(WT1 + frow * 128 + ((16 * g) ^ ((frow & 7) << 4)));
        short8 b1 = *(const short8*)(WT1 + frow * 128 + ((64 + 16 * g) ^ ((frow & 7) << 4)));
        f32x4 acc = {0.f, 0.f, 0.f, 0.f};
        acc = MFMA32(a0, b0, acc);
        acc = MFMA32(a1, b1, acc);
        float bval = bias[frow] * bscale;
        int mloc = wid * 16 + 4 * g;
        if (w3 < 2) {   // q,k: OT[m][c]
            #pragma unroll
            for (int r = 0; r < 4; ++r)
                ot[(mloc + r) * 72 + frow] = f2bf(acc[r] + bval);
        } else {        // v: OT[c][m]
            #pragma unroll
            for (int r = 0; r < 4; ++r)
                ot[frow * 72 + mloc + r] = f2bf(acc[r] + bval);
        }
    }
    __syncthreads();

    // frag-major coalesced global writes
    int mt_l = t >> 6, l = t & 63;
    size_t gmt = (size_t)rb * 4 + mt_l;
    if (w3 < 2) {
        unsigned short* dst = ((w3 == 0) ? qf : kf) + gmt * 1024;
        #pragma unroll
        for (int h = 0; h < 2; ++h) {
            u32x4 val = *(const u32x4*)(ot + (mt_l * 16 + (l & 15)) * 72 + h * 32 + 8 * (l >> 4));
            *(u32x4*)(dst + h * 512 + l * 8) = val;
        }
    } else {
        unsigned short* dst = vf + gmt * 1024;
        #pragma unroll
        for (int ct = 0; ct < 4; ++ct) {
            u32x2 val = *(const u32x2*)(ot + (ct * 16 + (l & 15)) * 72 + mt_l * 16 + 4 * (l >> 4));
            *(u32x2*)(dst + ct * 256 + l * 4) = val;
        }
    }
}

// ---------------- k2: partial row sums, no-LDS streaming, unroll-2 ----------------
// grid 1024: blk = b*256 + ns*64 + mb. Wave pins its m-tile A-frags, streams
// its n-quarter's 64 kf tiles two at a time with 2-tile-ahead prefetch.
__global__ __launch_bounds__(256, 4) void k2_rowsum(const unsigned short* __restrict__ qf,
                                                    const unsigned short* __restrict__ kf,
                                                    float* __restrict__ sbuf) {
    int t = threadIdx.x, blk = blockIdx.x;
    int b = blk >> 8, ns = (blk >> 6) & 3, mb = blk & 63;
    int lane = t & 63, wid = t >> 6, g = lane >> 4, ln = lane & 15;

    size_t mt_g = (size_t)b * 256 + mb * 4 + wid;
    short8 a0 = *(const short8*)(qf + mt_g * 1024 + lane * 8);
    short8 a1 = *(const short8*)(qf + mt_g * 1024 + 512 + lane * 8);

    const unsigned short* kfb = kf + ((size_t)b * 256 + ns * 64) * 1024 + lane * 8;
    short8 kA0 = *(const short8*)(kfb);
    short8 kA1 = *(const short8*)(kfb + 512);
    short8 kB0 = *(const short8*)(kfb + 1024);
    short8 kB1 = *(const short8*)(kfb + 1536);

    f32x4 z = {0.f, 0.f, 0.f, 0.f};
    float acc0 = 0.f, acc1 = 0.f, acc2 = 0.f, acc3 = 0.f;
    for (int it = 0; it < 32; ++it) {
        short8 nA0, nA1, nB0, nB1;
        if (it < 31) {   // prefetch tiles 2it+2, 2it+3
            const unsigned short* kp = kfb + (size_t)(2 * it + 2) * 1024;
            nA0 = *(const short8*)(kp);
            nA1 = *(const short8*)(kp + 512);
            nB0 = *(const short8*)(kp + 1024);
            nB1 = *(const short8*)(kp + 1536);
        }
        f32x4 eA = MFMA32(a1, kA1, MFMA32(a0, kA0, z));
        f32x4 eB = MFMA32(a1, kB1, MFMA32(a0, kB0, z));
        acc0 += EXP2(eA[0]); acc1 += EXP2(eA[1]);
        acc2 += EXP2(eA[2]); acc3 += EXP2(eA[3]);
        acc0 += EXP2(eB[0]); acc1 += EXP2(eB[1]);
        acc2 += EXP2(eB[2]); acc3 += EXP2(eB[3]);
        kA0 = nA0; kA1 = nA1; kB0 = nB0; kB1 = nB1;
    }
    #pragma unroll
    for (int msk = 1; msk < 16; msk <<= 1) {
        acc0 += __shfl_xor(acc0, msk);
        acc1 += __shfl_xor(acc1, msk);
        acc2 += __shfl_xor(acc2, msk);
        acc3 += __shfl_xor(acc3, msk);
    }
    if (ln == 0) {
        float* base = sbuf + b * 4096 + (mb * 4 + wid) * 16 + 4 * g;
        unsafeAtomicAdd(base + 0, acc0);
        unsafeAtomicAdd(base + 1, acc1);
        unsafeAtomicAdd(base + 2, acc2);
        unsafeAtomicAdd(base + 3, acc3);
    }
}

// ---------------- r2: lr = -log2(s) ; out <- x ----------------
__global__ __launch_bounds__(256) void r2_init(const float* __restrict__ sbuf,
                                               float* __restrict__ lrbuf,
                                               const float* __restrict__ x,
                                               float* __restrict__ outp) {
    int tid = blockIdx.x * 256 + threadIdx.x;   // grid 1024
    if (tid < 16384) lrbuf[tid] = -__log2f(sbuf[tid]);
    f32x4 v = *(const f32x4*)(x + 4 * (size_t)tid);
    *(f32x4*)(outp + 4 * (size_t)tid) = v;
}

// ---------------- k3: out += gamma * exp2(e'+lr) @ v, no-LDS, unroll-2 ----------------
// grid 1024: blk = b*256 + ms*64 + nblk. Wave pins its n-tile kf frags,
// streams its m-quarter's 64 tiles two at a time (2 independent chains),
// prefetching tiles 2it+2,2it+3 at iteration top.
__global__ __launch_bounds__(256, 4) void k3_out(const unsigned short* __restrict__ qf,
                                                 const unsigned short* __restrict__ kf,
                                                 const unsigned short* __restrict__ vf,
                                                 const float* __restrict__ lrbuf,
                                                 const float* __restrict__ gamma,
                                                 float* __restrict__ outp) {
    int t = threadIdx.x, blk = blockIdx.x;
    int b = blk >> 8, ms = (blk >> 6) & 3, nblk = blk & 63;
    int lane = t & 63, wid = t >> 6, g = lane >> 4, ln = lane & 15;

    size_t nt_g = (size_t)b * 256 + nblk * 4 + wid;
    short8 kb0 = *(const short8*)(kf + nt_g * 1024 + lane * 8);
    short8 kb1 = *(const short8*)(kf + nt_g * 1024 + 512 + lane * 8);

    size_t mtbase = (size_t)b * 256 + ms * 64;
    const unsigned short* qb = qf + mtbase * 1024 + lane * 8;
    const unsigned short* vb = vf + mtbase * 1024 + lane * 4;
    const float* lrb = lrbuf + b * 4096 + ms * 1024 + 4 * g;

    // tiles 0 (A) and 1 (B)
    short8 aA0 = *(const short8*)(qb);
    short8 aA1 = *(const short8*)(qb + 512);
    short4b vA0 = *(const short4b*)(vb);
    short4b vA1 = *(const short4b*)(vb + 256);
    short4b vA2 = *(const short4b*)(vb + 512);
    short4b vA3 = *(const short4b*)(vb + 768);
    f32x4 lcA = *(const f32x4*)(lrb);
    short8 aB0 = *(const short8*)(qb + 1024);
    short8 aB1 = *(const short8*)(qb + 1536);
    short4b vB0 = *(const short4b*)(vb + 1024);
    short4b vB1 = *(const short4b*)(vb + 1280);
    short4b vB2 = *(const short4b*)(vb + 1536);
    short4b vB3 = *(const short4b*)(vb + 1792);
    f32x4 lcB = *(const f32x4*)(lrb + 16);

    f32x4 z = {0.f, 0.f, 0.f, 0.f};
    f32x4 oacc[4] = {z, z, z, z};

    for (int it = 0; it < 32; ++it) {
        short8 nA0, nA1, nB0, nB1;
        short4b wA0, wA1, wA2, wA3, wB0, wB1, wB2, wB3;
        f32x4 plA, plB;
        if (it < 31) {   // prefetch tiles 2it+2 (A) and 2it+3 (B)
            int mt2 = 2 * it + 2;
            const unsigned short* qp = qb + (size_t)mt2 * 1024;
            nA0 = *(const short8*)(qp);
            nA1 = *(const short8*)(qp + 512);
            nB0 = *(const short8*)(qp + 1024);
            nB1 = *(const short8*)(qp + 1536);
            const unsigned short* vp = vb + (size_t)mt2 * 1024;
            wA0 = *(const short4b*)(vp);
            wA1 = *(const short4b*)(vp + 256);
            wA2 = *(const short4b*)(vp + 512);
            wA3 = *(const short4b*)(vp + 768);
            wB0 = *(const short4b*)(vp + 1024);
            wB1 = *(const short4b*)(vp + 1280);
            wB2 = *(const short4b*)(vp + 1536);
            wB3 = *(const short4b*)(vp + 1792);
            plA = *(const f32x4*)(lrb + mt2 * 16);
            plB = *(const f32x4*)(lrb + mt2 * 16 + 16);
        }
        // chain A
        f32x4 eA = MFMA32(aA1, kb1, MFMA32(aA0, kb0, lcA));
        float pA0 = EXP2(eA[0]), pA1 = EXP2(eA[1]), pA2 = EXP2(eA[2]), pA3 = EXP2(eA[3]);
        u32x2 pwA = { pack2t(pA0, pA1), pack2t(pA2, pA3) };
        short4b paA = __builtin_bit_cast(short4b, pwA);
        // chain B (independent)
        f32x4 eB = MFMA32(aB1, kb1, MFMA32(aB0, kb0, lcB));
        float pB0 = EXP2(eB[0]), pB1 = EXP2(eB[1]), pB2 = EXP2(eB[2]), pB3 = EXP2(eB[3]);
        u32x2 pwB = { pack2t(pB0, pB1), pack2t(pB2, pB3) };
        short4b paB = __builtin_bit_cast(short4b, pwB);

        oacc[0] = MFMA16(paA, vA0, oacc[0]);
        oacc[1] = MFMA16(paA, vA1, oacc[1]);
        oacc[2] = MFMA16(paA, vA2, oacc[2]);
        oacc[3] = MFMA16(paA, vA3, oacc[3]);
        oacc[0] = MFMA16(paB, vB0, oacc[0]);
        oacc[1] = MFMA16(paB, vB1, oacc[1]);
        oacc[2] = MFMA16(paB, vB2, oacc[2]);
        oacc[3] = MFMA16(paB, vB3, oacc[3]);

        aA0 = nA0; aA1 = nA1; aB0 = nB0; aB1 = nB1;
        vA0 = wA0; vA1 = wA1; vA2 = wA2; vA3 = wA3;
        vB0 = wB0; vB1 = wB1; vB2 = wB2; vB3 = wB3;
        lcA = plA; lcB = plB;
    }

    float gm = gamma[0];
    int nr = b * 4096 + (nblk * 4 + wid) * 16 + 4 * g;
    #pragma unroll
    for (int ct = 0; ct < 4; ++ct) {
        #pragma unroll
        for (int r = 0; r < 4; ++r)
            unsafeAtomicAdd(outp + (size_t)(nr + r) * 64 + ct * 16 + ln, gm * oacc[ct][r]);
    }
}

extern "C" void kernel_launch(void* const* d_in, const int* in_sizes, int n_in,
                              void* d_out, int out_size, void* d_ws, size_t ws_size,
                              hipStream_t stream) {
    const float* x  = (const float*)d_in[0];
    const float* Wq = (const float*)d_in[1];
    const float* bq = (const float*)d_in[2];
    const float* Wk = (const float*)d_in[3];
    const float* bk = (const float*)d_in[4];
    const float* Wv = (const float*)d_in[5];
    const float* bv = (const float*)d_in[6];
    const float* gm = (const float*)d_in[7];
    char* ws = (char*)d_ws;
    float* outp = (float*)d_out;

    unsigned short* qf = (unsigned short*)(ws + OFF_Q);
    unsigned short* kf = (unsigned short*)(ws + OFF_K);
    unsigned short* vf = (unsigned short*)(ws + OFF_VT);
    unsigned short* wt = (unsigned short*)(ws + OFF_WT);
    float* sbuf        = (float*)(ws + OFF_S);
    float* lrbuf       = (float*)(ws + OFF_LR);

    k0z<<<64, 256, 0, stream>>>(Wq, Wk, Wv, wt, sbuf);
    k1_proj<<<768, 256, 0, stream>>>(x, wt, bq, bk, bv, qf, kf, vf);
    k2_rowsum<<<1024, 256, 0, stream>>>(qf, kf, sbuf);
    r2_init<<<1024, 256, 0, stream>>>(sbuf, lrbuf, x, outp);
    k3_out<<<1024, 256, 0, stream>>>(qf, kf, vf, lrbuf, gm, outp);
}

// Round 11
// 126.575 us; speedup vs baseline: 1.2870x; 1.2341x over previous
//
#include <hip/hip_runtime.h>
#include <hip/hip_bf16.h>

// PAM module: B=4, N=4096 (64x64), C=64.
// out[b,n,c] = gamma * sum_m softmax_row(q@k^T)[m,n] * v[m,c] + x[b,n,c]
//
// bf16 MFMA; energy recomputed. log2e folded into Wq/bq; softmax normalizer
// folded into QK MFMA C-init (lr = -log2(rowsum)); P built in registers
// (K=16 PV MFMA identity), truncation bf16 pack.
// q/k/v^T stored MFMA-FRAGMENT-MAJOR (producer k1), so staged LDS tiles are
// lane-linear: global_load_lds DMA dest (uniform base + lane*16) IS the
// fragment layout, and all ds_reads are conflict-free b128/b64.
// R11: k2/k3 stream via double-buffered LDS fed by global_load_lds
// (hardware async the compiler cannot sink -- R10's register prefetch was
// rewritten to point-of-use loads, VGPR=40 proved it). 1 barrier/iter.
//  k0z: W -> W^T bf16 (Wq scaled by log2e), zero s-buffer
//  k1 : projections (grid 768); outputs written frag-major via LDS staging
//  k2 : partial rowsums, n-split 4, LDS-dbuf DMA streaming (grid 1024)
//  r2 : lr = -log2(s) ; out <- x
//  k3 : out += gamma * exp2(e'+lr) @ v, m-split 4, LDS-dbuf DMA (grid 1024)

typedef __attribute__((ext_vector_type(8))) short short8;
typedef __attribute__((ext_vector_type(4))) short short4b;
typedef __attribute__((ext_vector_type(4))) float f32x4;
typedef __attribute__((ext_vector_type(4))) unsigned int u32x4;
typedef __attribute__((ext_vector_type(2))) unsigned int u32x2;

#define DEV static __device__ __forceinline__
#define LOG2E 1.4426950408889634f

DEV unsigned short f2bf(float f) {
    __hip_bfloat16 h = __float2bfloat16(f);
    return __builtin_bit_cast(unsigned short, h);
}
DEV unsigned int pack2(float lo, float hi) {
    return (unsigned int)f2bf(lo) | ((unsigned int)f2bf(hi) << 16);
}
DEV unsigned int pack2t(float lo, float hi) {   // truncation-pack (P>=0, no NaN)
    unsigned int ul = __builtin_bit_cast(unsigned int, lo);
    unsigned int uh = __builtin_bit_cast(unsigned int, hi);
    return (uh & 0xffff0000u) | (ul >> 16);
}
DEV f32x4 MFMA32(short8 a, short8 b, f32x4 c) {
    return __builtin_amdgcn_mfma_f32_16x16x32_bf16(a, b, c, 0, 0, 0);
}
DEV f32x4 MFMA16(short4b a, short4b b, f32x4 c) {
#if __has_builtin(__builtin_amdgcn_mfma_f32_16x16x16_bf16)
    return __builtin_amdgcn_mfma_f32_16x16x16_bf16(a, b, c, 0, 0, 0);
#else
    return __builtin_amdgcn_mfma_f32_16x16x16bf16_1k(a, b, c, 0, 0, 0);
#endif
}
DEV float EXP2(float x) {
#if __has_builtin(__builtin_amdgcn_exp2f)
    return __builtin_amdgcn_exp2f(x);
#else
    return exp2f(x);
#endif
}
// async global->LDS DMA, 16B/lane: dest = lds_base(uniform) + lane*16,
// src = per-lane global address. Cannot be sunk/serialized by the compiler.
DEV void gld16(const void* g, void* l) {
    __builtin_amdgcn_global_load_lds(
        (const __attribute__((address_space(1))) unsigned int*)g,
        (__attribute__((address_space(3))) unsigned int*)l,
        16, 0, 0);
}

// Fragment-major layouts (shorts), tile = global 16-row tile index [0,1024):
//  qf/kf: [tile][h(2)][lane(64)][e(8)] ; element = q[tile*16+(l&15)][h*32+8*(l>>4)+e]
//  vf   : [tile][ct(4)][lane(64)][e(4)]; element = v[tile*16+4*(l>>4)+e][ct*16+(l&15)]
// ws layout (bytes)
#define OFF_Q    0u
#define OFF_K    2097152u
#define OFF_VT   4194304u
#define OFF_WT   6291456u
#define OFF_S    6316032u
#define OFF_LR   6381568u

// ---------------- k0z: weight transpose (+log2e on Wq) + zero s ----------------
__global__ __launch_bounds__(256) void k0z(const float* __restrict__ Wq,
                                           const float* __restrict__ Wk,
                                           const float* __restrict__ Wv,
                                           unsigned short* __restrict__ wt,
                                           float* __restrict__ sbuf) {
    int e = blockIdx.x * 256 + threadIdx.x;   // grid 64 -> [0,16384)
    sbuf[e] = 0.0f;
    if (e < 3 * 4096) {
        int w3 = e >> 12, rem = e & 4095, f = rem >> 6, c = rem & 63;
        const float* W = (w3 == 0) ? Wq : (w3 == 1) ? Wk : Wv;
        float s = (w3 == 0) ? LOG2E : 1.0f;
        wt[e] = f2bf(W[c * 64 + f] * s);   // wt[w3][f][c] = W[c][f] * s
    }
}

// ---------------- k1: projections -> frag-major outputs (grid 768) ----------------
__global__ __launch_bounds__(256) void k1_proj(const float* __restrict__ x,
                                               const unsigned short* __restrict__ wt,
                                               const float* __restrict__ bq,
                                               const float* __restrict__ bk,
                                               const float* __restrict__ bv,
                                               unsigned short* __restrict__ qf,
                                               unsigned short* __restrict__ kf,
                                               unsigned short* __restrict__ vf) {
    __shared__ __align__(16) char XT[8192];
    __shared__ __align__(16) char WT1[8192];
    __shared__ __align__(16) char OT[9216];
    int t = threadIdx.x, blk = blockIdx.x;
    int w3 = blk >> 8, rb = blk & 255;

    {   // stage x tile (fp32 -> bf16, swizzled)
        int m = t >> 2, q4 = t & 3;
        const f32x4* xs = (const f32x4*)(x + (size_t)(rb * 64 + m) * 64 + q4 * 16);
        f32x4 fa = xs[0], f2 = xs[1], fc = xs[2], fd = xs[3];
        u32x4 u0 = { pack2(fa[0],fa[1]), pack2(fa[2],fa[3]), pack2(f2[0],f2[1]), pack2(f2[2],f2[3]) };
        u32x4 u1 = { pack2(fc[0],fc[1]), pack2(fc[2],fc[3]), pack2(fd[0],fd[1]), pack2(fd[2],fd[3]) };
        int sw = (m & 7) << 4;
        *(u32x4*)(XT + m * 128 + ((q4 * 32) ^ sw)) = u0;
        *(u32x4*)(XT + m * 128 + ((q4 * 32 + 16) ^ sw)) = u1;
    }
    {   // stage this projection's W^T
        int f = t >> 2, q4 = t & 3;
        const u32x4* s = (const u32x4*)(wt + w3 * 4096 + f * 64 + q4 * 16);
        u32x4 u0 = s[0], u1 = s[1];
        int sw = (f & 7) << 4;
        *(u32x4*)(WT1 + f * 128 + ((q4 * 32) ^ sw)) = u0;
        *(u32x4*)(WT1 + f * 128 + ((q4 * 32 + 16) ^ sw)) = u1;
    }
    __syncthreads();

    int lane = t & 63, wid = t >> 6, g = lane >> 4, ln = lane & 15;
    int arow = wid * 16 + ln;
    short8 a0 = *(const short8*)(XT + arow * 128 + ((16 * g) ^ ((arow & 7) << 4)));
    short8 a1 = *(const short8*)(XT + arow * 128 + ((64 + 16 * g) ^ ((arow & 7) << 4)));
    const float* bias = (w3 == 0) ? bq : (w3 == 1) ? bk : bv;
    float bscale = (w3 == 0) ? LOG2E : 1.0f;

    unsigned short* ot = (unsigned short*)OT;
    #pragma unroll
    for (int fb = 0; fb < 4; ++fb) {
        int frow = fb * 16 + ln;
        short8 b0 = *(const short8*)(WT1 + frow * 128 + ((16 * g) ^ ((frow & 7) << 4)));
        short8 b1 = *(const short8*)(WT1 + frow * 128 + ((64 + 16 * g) ^ ((frow & 7) << 4)));
        f32x4 acc = {0.f, 0.f, 0.f, 0.f};
        acc = MFMA32(a0, b0, acc);
        acc = MFMA32(a1, b1, acc);
        float bval = bias[frow] * bscale;
        int mloc = wid * 16 + 4 * g;
        if (w3 < 2) {   // q,k: OT[m][c]
            #pragma unroll
            for (int r = 0; r < 4; ++r)
                ot[(mloc + r) * 72 + frow] = f2bf(acc[r] + bval);
        } else {        // v: OT[c][m]
            #pragma unroll
            for (int r = 0; r < 4; ++r)
                ot[frow * 72 + mloc + r] = f2bf(acc[r] + bval);
        }
    }
    __syncthreads();

    // frag-major coalesced global writes
    int mt_l = t >> 6, l = t & 63;
    size_t gmt = (size_t)rb * 4 + mt_l;
    if (w3 < 2) {
        unsigned short* dst = ((w3 == 0) ? qf : kf) + gmt * 1024;
        #pragma unroll
        for (int h = 0; h < 2; ++h) {
            u32x4 val = *(const u32x4*)(ot + (mt_l * 16 + (l & 15)) * 72 + h * 32 + 8 * (l >> 4));
            *(u32x4*)(dst + h * 512 + l * 8) = val;
        }
    } else {
        unsigned short* dst = vf + gmt * 1024;
        #pragma unroll
        for (int ct = 0; ct < 4; ++ct) {
            u32x2 val = *(const u32x2*)(ot + (ct * 16 + (l & 15)) * 72 + mt_l * 16 + 4 * (l >> 4));
            *(u32x2*)(dst + ct * 256 + l * 4) = val;
        }
    }
}

// ---------------- k2: partial rowsums, LDS-dbuf DMA streaming ----------------
// grid 1024: blk = b*256 + ns*64 + mb. Wave pins its m-tile A-frags; block
// streams its n-quarter's 64 kf tiles 2 at a time via global_load_lds dbuf.
__global__ __launch_bounds__(256, 4) void k2_rowsum(const unsigned short* __restrict__ qf,
                                                    const unsigned short* __restrict__ kf,
                                                    float* __restrict__ sbuf) {
    __shared__ __align__(16) char KB[2][4096];   // 2 tiles (frag-major) per buf
    int t = threadIdx.x, blk = blockIdx.x;
    int b = blk >> 8, ns = (blk >> 6) & 3, mb = blk & 63;
    int lane = t & 63, wid = t >> 6, g = lane >> 4, ln = lane & 15;

    size_t mt_g = (size_t)b * 256 + mb * 4 + wid;
    short8 a0 = *(const short8*)(qf + mt_g * 1024 + lane * 8);
    short8 a1 = *(const short8*)(qf + mt_g * 1024 + 512 + lane * 8);

    const char* kbytes = (const char*)(kf + ((size_t)b * 256 + ns * 64) * 1024);
    // STAGE(buf,it): wave wid DMAs its 1KB region of the 4KB tile-pair it
    #define K2STAGE(BUF, IT) \
        gld16(kbytes + (size_t)(IT) * 4096 + wid * 1024 + lane * 16, KB[BUF] + wid * 1024)

    K2STAGE(0, 0);
    __syncthreads();

    f32x4 z = {0.f, 0.f, 0.f, 0.f};
    float acc0 = 0.f, acc1 = 0.f, acc2 = 0.f, acc3 = 0.f;
    int buf = 0;
    for (int it = 0; it < 32; ++it) {
        if (it < 31) K2STAGE(buf ^ 1, it + 1);   // async DMA overlaps compute
        const char* kt = KB[buf];
        short8 kA0 = *(const short8*)(kt + lane * 16);
        short8 kA1 = *(const short8*)(kt + 1024 + lane * 16);
        short8 kB0 = *(const short8*)(kt + 2048 + lane * 16);
        short8 kB1 = *(const short8*)(kt + 3072 + lane * 16);
        f32x4 eA = MFMA32(a1, kA1, MFMA32(a0, kA0, z));
        f32x4 eB = MFMA32(a1, kB1, MFMA32(a0, kB0, z));
        acc0 += EXP2(eA[0]); acc1 += EXP2(eA[1]);
        acc2 += EXP2(eA[2]); acc3 += EXP2(eA[3]);
        acc0 += EXP2(eB[0]); acc1 += EXP2(eB[1]);
        acc2 += EXP2(eB[2]); acc3 += EXP2(eB[3]);
        __syncthreads();
        buf ^= 1;
    }
    #pragma unroll
    for (int msk = 1; msk < 16; msk <<= 1) {
        acc0 += __shfl_xor(acc0, msk);
        acc1 += __shfl_xor(acc1, msk);
        acc2 += __shfl_xor(acc2, msk);
        acc3 += __shfl_xor(acc3, msk);
    }
    if (ln == 0) {
        float* base = sbuf + b * 4096 + (mb * 4 + wid) * 16 + 4 * g;
        unsafeAtomicAdd(base + 0, acc0);
        unsafeAtomicAdd(base + 1, acc1);
        unsafeAtomicAdd(base + 2, acc2);
        unsafeAtomicAdd(base + 3, acc3);
    }
}

// ---------------- r2: lr = -log2(s) ; out <- x ----------------
__global__ __launch_bounds__(256) void r2_init(const float* __restrict__ sbuf,
                                               float* __restrict__ lrbuf,
                                               const float* __restrict__ x,
                                               float* __restrict__ outp) {
    int tid = blockIdx.x * 256 + threadIdx.x;   // grid 1024
    if (tid < 16384) lrbuf[tid] = -__log2f(sbuf[tid]);
    f32x4 v = *(const f32x4*)(x + 4 * (size_t)tid);
    *(f32x4*)(outp + 4 * (size_t)tid) = v;
}

// ---------------- k3: out += gamma*exp2(e'+lr)@v, LDS-dbuf DMA streaming ----------------
// grid 1024: blk = b*256 + ms*64 + nblk. Wave pins its n-tile kf frags; block
// streams its m-quarter's 64 q+v tiles 2 at a time via global_load_lds dbuf.
// lr staged once (4KB) into LDS, read by broadcast.
__global__ __launch_bounds__(256, 4) void k3_out(const unsigned short* __restrict__ qf,
                                                 const unsigned short* __restrict__ kf,
                                                 const unsigned short* __restrict__ vf,
                                                 const float* __restrict__ lrbuf,
                                                 const float* __restrict__ gamma,
                                                 float* __restrict__ outp) {
    __shared__ __align__(16) char QV[2][8192];   // per buf: q 2 tiles | v 2 tiles
    __shared__ __align__(16) char LRS[4096];     // lr for the whole m-quarter
    int t = threadIdx.x, blk = blockIdx.x;
    int b = blk >> 8, ms = (blk >> 6) & 3, nblk = blk & 63;
    int lane = t & 63, wid = t >> 6, g = lane >> 4, ln = lane & 15;

    size_t nt_g = (size_t)b * 256 + nblk * 4 + wid;
    short8 kb0 = *(const short8*)(kf + nt_g * 1024 + lane * 8);
    short8 kb1 = *(const short8*)(kf + nt_g * 1024 + 512 + lane * 8);

    size_t mtbase = (size_t)b * 256 + ms * 64;
    const char* qbytes = (const char*)(qf + mtbase * 1024);
    const char* vbytes = (const char*)(vf + mtbase * 1024);
    const float* lrsrc = lrbuf + b * 4096 + ms * 1024;

    // stage lr once: wave wid DMAs its 1KB region
    gld16(lrsrc + wid * 256 + lane * 4, LRS + wid * 1024);
    // STAGE(buf,it): 8 x 1KB regions (q: r<4, v: r>=4); wave wid does r=2w,2w+1
    #define K3STAGE(BUF, IT)                                                      \
        do {                                                                      \
            int r0_ = 2 * wid, r1_ = 2 * wid + 1;                                 \
            const char* s0_ = (r0_ < 4 ? qbytes + r0_ * 1024                      \
                                       : vbytes + (r0_ - 4) * 1024)               \
                              + (size_t)(IT) * 4096 + lane * 16;                  \
            const char* s1_ = (r1_ < 4 ? qbytes + r1_ * 1024                      \
                                       : vbytes + (r1_ - 4) * 1024)               \
                              + (size_t)(IT) * 4096 + lane * 16;                  \
            gld16(s0_, QV[BUF] + r0_ * 1024);                                     \
            gld16(s1_, QV[BUF] + r1_ * 1024);                                     \
        } while (0)

    K3STAGE(0, 0);
    __syncthreads();

    f32x4 z = {0.f, 0.f, 0.f, 0.f};
    f32x4 oacc[4] = {z, z, z, z};
    int buf = 0;
    for (int it = 0; it < 32; ++it) {
        if (it < 31) K3STAGE(buf ^ 1, it + 1);   // async DMA overlaps compute
        const char* qt = QV[buf];
        const char* vt = QV[buf] + 4096;
        f32x4 lcA = *(const f32x4*)(LRS + it * 128 + g * 16);
        f32x4 lcB = *(const f32x4*)(LRS + it * 128 + 64 + g * 16);
        short8 aA0 = *(const short8*)(qt + lane * 16);
        short8 aA1 = *(const short8*)(qt + 1024 + lane * 16);
        short8 aB0 = *(const short8*)(qt + 2048 + lane * 16);
        short8 aB1 = *(const short8*)(qt + 3072 + lane * 16);

        // chain A
        f32x4 eA = MFMA32(aA1, kb1, MFMA32(aA0, kb0, lcA));
        float pA0 = EXP2(eA[0]), pA1 = EXP2(eA[1]), pA2 = EXP2(eA[2]), pA3 = EXP2(eA[3]);
        u32x2 pwA = { pack2t(pA0, pA1), pack2t(pA2, pA3) };
        short4b paA = __builtin_bit_cast(short4b, pwA);
        // chain B (independent)
        f32x4 eB = MFMA32(aB1, kb1, MFMA32(aB0, kb0, lcB));
        float pB0 = EXP2(eB[0]), pB1 = EXP2(eB[1]), pB2 = EXP2(eB[2]), pB3 = EXP2(eB[3]);
        u32x2 pwB = { pack2t(pB0, pB1), pack2t(pB2, pB3) };
        short4b paB = __builtin_bit_cast(short4b, pwB);

        #pragma unroll
        for (int ct = 0; ct < 4; ++ct) {
            short4b vA = *(const short4b*)(vt + ct * 512 + lane * 8);
            short4b vB = *(const short4b*)(vt + 2048 + ct * 512 + lane * 8);
            oacc[ct] = MFMA16(paA, vA, oacc[ct]);
            oacc[ct] = MFMA16(paB, vB, oacc[ct]);
        }
        __syncthreads();
        buf ^= 1;
    }

    float gm = gamma[0];
    int nr = b * 4096 + (nblk * 4 + wid) * 16 + 4 * g;
    #pragma unroll
    for (int ct = 0; ct < 4; ++ct) {
        #pragma unroll
        for (int r = 0; r < 4; ++r)
            unsafeAtomicAdd(outp + (size_t)(nr + r) * 64 + ct * 16 + ln, gm * oacc[ct][r]);
    }
}

extern "C" void kernel_launch(void* const* d_in, const int* in_sizes, int n_in,
                              void* d_out, int out_size, void* d_ws, size_t ws_size,
                              hipStream_t stream) {
    const float* x  = (const float*)d_in[0];
    const float* Wq = (const float*)d_in[1];
    const float* bq = (const float*)d_in[2];
    const float* Wk = (const float*)d_in[3];
    const float* bk = (const float*)d_in[4];
    const float* Wv = (const float*)d_in[5];
    const float* bv = (const float*)d_in[6];
    const float* gm = (const float*)d_in[7];
    char* ws = (char*)d_ws;
    float* outp = (float*)d_out;

    unsigned short* qf = (unsigned short*)(ws + OFF_Q);
    unsigned short* kf = (unsigned short*)(ws + OFF_K);
    unsigned short* vf = (unsigned short*)(ws + OFF_VT);
    unsigned short* wt = (unsigned short*)(ws + OFF_WT);
    float* sbuf        = (float*)(ws + OFF_S);
    float* lrbuf       = (float*)(ws + OFF_LR);

    k0z<<<64, 256, 0, stream>>>(Wq, Wk, Wv, wt, sbuf);
    k1_proj<<<768, 256, 0, stream>>>(x, wt, bq, bk, bv, qf, kf, vf);
    k2_rowsum<<<1024, 256, 0, stream>>>(qf, kf, sbuf);
    r2_init<<<1024, 256, 0, stream>>>(sbuf, lrbuf, x, outp);
    k3_out<<<1024, 256, 0, stream>>>(qf, kf, vf, lrbuf, gm, outp);
}